// Round 2
// baseline (258.525 us; speedup 1.0000x reference)
//
#include <hip/hip_runtime.h>

// FGPillarMaxPooling on MI355X (gfx950)
// Output: (B*GH*GW, COUT) fp32 = 33,554,432 floats = 128 MiB.
//
// R2 change: runtime hipMemsetAsync ran at only ~0.9 TB/s (139 us for 128 MiB,
// bigger than the compute kernel). Replace with a grid-stride float4 zero
// kernel (streaming 16B stores -> expect ~25 us).
//
// Atomic pass (unchanged from R1): h = relu(gf @ W) >= 0, empty segments -> 0,
// so zero-init + unsigned atomicMax on float bits is exact. One 32-lane group
// per point, lane == channel; the 32 lanes hit one contiguous 128 B span.

#define GW 512
#define GH 512
#define COUT 32
#define PTS_PER_BLOCK 8   // 256 threads / 32 channels

__global__ __launch_bounds__(256) void zero_out4(float4* __restrict__ out, int n4) {
    int stride = gridDim.x * blockDim.x;
    float4 z = make_float4(0.f, 0.f, 0.f, 0.f);
    for (int i = blockIdx.x * blockDim.x + threadIdx.x; i < n4; i += stride)
        out[i] = z;
}

__global__ __launch_bounds__(256) void pillar_fwd(
    const float* __restrict__ xyz,        // (N,3)
    const int*   __restrict__ cnt,        // (B,)
    const float4* __restrict__ feat,      // (N,4) as float4
    const float* __restrict__ W,          // (7,32) row-major
    unsigned int* __restrict__ out,       // (B*GH*GW, 32) float bits
    int N, int B)
{
    __shared__ float sW[7 * COUT];
    int tid = threadIdx.x;
    if (tid < 7 * COUT) sW[tid] = W[tid];
    __syncthreads();

    int p = blockIdx.x * PTS_PER_BLOCK + (tid >> 5);
    int c = tid & 31;
    if (p >= N) return;

    float x = xyz[3 * p + 0];
    float y = xyz[3 * p + 1];
    float z = xyz[3 * p + 2];

    // batch index from prefix sums of cnt (B small; same-address loads broadcast)
    int b = 0, acc = 0;
    for (int k = 0; k < B; ++k) {
        acc += cnt[k];
        b += (p >= acc) ? 1 : 0;
    }

    // pillar cell — IEEE division to match the reference's floor decisions
    int px = (int)floorf((x - (-51.2f)) / 0.2f);
    int py = (int)floorf((y - (-51.2f)) / 0.2f);
    px = min(max(px, 0), GW - 1);
    py = min(max(py, 0), GH - 1);

    float cx = ((float)px + 0.5f) * 0.2f + (-51.2f);
    float cy = ((float)py + 0.5f) * 0.2f + (-51.2f);
    // cz = 0.5*(-5.0 + 3.0) = -1.0  ->  z - cz = z + 1.0
    float g4 = x - cx;
    float g5 = y - cy;
    float g6 = z + 1.0f;

    float4 f = feat[p];

    float h = f.x * sW[0 * COUT + c]
            + f.y * sW[1 * COUT + c]
            + f.z * sW[2 * COUT + c]
            + f.w * sW[3 * COUT + c]
            + g4  * sW[4 * COUT + c]
            + g5  * sW[5 * COUT + c]
            + g6  * sW[6 * COUT + c];
    h = fmaxf(h, 0.0f);

    unsigned int seg = (unsigned int)b * (GH * GW) + (unsigned int)py * GW + (unsigned int)px;
    atomicMax(out + (size_t)seg * COUT + c, __float_as_uint(h));
}

extern "C" void kernel_launch(void* const* d_in, const int* in_sizes, int n_in,
                              void* d_out, int out_size, void* d_ws, size_t ws_size,
                              hipStream_t stream) {
    const float*  xyz  = (const float*)d_in[0];
    const int*    cnt  = (const int*)d_in[1];
    const float4* feat = (const float4*)d_in[2];
    const float*  W    = (const float*)d_in[3];
    unsigned int* out  = (unsigned int*)d_out;

    int N = in_sizes[0] / 3;
    int B = in_sizes[1];

    // Fast zero of d_out (harness poisons it to 0xAA before every launch).
    int n4 = out_size / 4;                       // 8,388,608 float4s
    zero_out4<<<2048, 256, 0, stream>>>((float4*)d_out, n4);

    int grid = (N + PTS_PER_BLOCK - 1) / PTS_PER_BLOCK;
    pillar_fwd<<<grid, 256, 0, stream>>>(xyz, cnt, feat, W, out, N, B);
}